// Round 4
// baseline (1239.429 us; speedup 1.0000x reference)
//
#include <hip/hip_runtime.h>

// GAT 3-layer forward, MI355X. Round 4:
//  - CSR-by-dst built on device each call (hist + scan + scatter), no float atomics.
//  - wave-per-node aggregation, readfirstlane-scalarized csr/rowptr, depth-3
//    gather pipeline (round 3: agg512 226->187us, VALUBusy 55%).
//  - THIS ROUND: non-temporal g store in agg512 + non-temporal A-loads in the
//    streamed-once GEMMs (x, g). Round-3 counters showed agg512 FETCH=295MB vs
//    ~36MB ideal: the 200MB g write stream evicts h1 (25.6MB) from L3, turning
//    L3-hit gathers into HBM misses. nt keeps h1 resident.
//  - layer2: aggregate h1 per head (g=[N,8,64]) then GEMM with rearranged W2.

#define NNODE 100000
#define NEDGE 1600000
#define ETOT  (NNODE + NEDGE)   // 1,700,000 incl self-loops
#define FIN   512
#define HID   64
#define NHEAD 8
#define NCLS  40

typedef float v4f __attribute__((ext_vector_type(4)));

static __device__ __forceinline__ float lrelu(float x) { return x > 0.f ? x : 0.2f * x; }
static __device__ __forceinline__ int rfl(int v) { return __builtin_amdgcn_readfirstlane(v); }

// ---------------- CSR build ----------------
__global__ __launch_bounds__(256) void k_hist(const int* __restrict__ ei, int* __restrict__ deg) {
    int e = blockIdx.x * 256 + threadIdx.x;
    if (e >= ETOT) return;
    int dst = (e < NEDGE) ? ei[NEDGE + e] : (e - NEDGE);
    atomicAdd(&deg[dst], 1);
}

__global__ __launch_bounds__(256) void k_scan1(const int* __restrict__ deg, int* __restrict__ rowptr,
                                               int* __restrict__ bsum) {
    __shared__ int sm[256];
    int b = blockIdx.x, t = threadIdx.x;
    int base = b * 1024 + t * 4;
    int v0=0,v1=0,v2=0,v3=0;
    if (base + 0 < NNODE) v0 = deg[base + 0];
    if (base + 1 < NNODE) v1 = deg[base + 1];
    if (base + 2 < NNODE) v2 = deg[base + 2];
    if (base + 3 < NNODE) v3 = deg[base + 3];
    int tsum = v0 + v1 + v2 + v3;
    sm[t] = tsum;
    __syncthreads();
    int val = tsum;
    for (int off = 1; off < 256; off <<= 1) {
        int y = (t >= off) ? sm[t - off] : 0;
        __syncthreads();
        val += y;
        sm[t] = val;
        __syncthreads();
    }
    int ex = val - tsum;
    if (base + 0 < NNODE) rowptr[base + 0] = ex;
    if (base + 1 < NNODE) rowptr[base + 1] = ex + v0;
    if (base + 2 < NNODE) rowptr[base + 2] = ex + v0 + v1;
    if (base + 3 < NNODE) rowptr[base + 3] = ex + v0 + v1 + v2;
    if (t == 255) bsum[b] = val;
}

__global__ __launch_bounds__(256) void k_scan2(int* __restrict__ bsum, int nb) {
    __shared__ int sm[256];
    int t = threadIdx.x;
    int v = (t < nb) ? bsum[t] : 0;
    sm[t] = v;
    __syncthreads();
    int val = v;
    for (int off = 1; off < 256; off <<= 1) {
        int y = (t >= off) ? sm[t - off] : 0;
        __syncthreads();
        val += y;
        sm[t] = val;
        __syncthreads();
    }
    if (t < nb) bsum[t] = val - v;
}

__global__ __launch_bounds__(256) void k_scan3(int* __restrict__ rowptr, const int* __restrict__ bsum) {
    int i = blockIdx.x * 256 + threadIdx.x;
    if (i < NNODE) rowptr[i] += bsum[i >> 10];
    if (i == 0) rowptr[NNODE] = ETOT;
}

__global__ __launch_bounds__(256) void k_scatter(const int* __restrict__ ei, const int* __restrict__ rowptr,
                                                 int* __restrict__ fill, int* __restrict__ csr) {
    int e = blockIdx.x * 256 + threadIdx.x;
    if (e >= ETOT) return;
    int s, d;
    if (e < NEDGE) { s = ei[e]; d = ei[NEDGE + e]; } else { s = e - NEDGE; d = s; }
    int pos = rowptr[d] + atomicAdd(&fill[d], 1);
    csr[pos] = s;
}

// ---------------- generic fp32 GEMM: C[NrowsxNC] = A[NrowsxK] @ B[KxNC] ----------------
// NTA: non-temporal A loads (A is streamed exactly once; don't pollute L2/L3).
template <bool NTA>
__global__ __launch_bounds__(256) void k_gemm(const float* __restrict__ A, const float* __restrict__ B,
                                              float* __restrict__ C, int Nrows, int K, int NC) {
    __shared__ float As[32][68];
    __shared__ float Bs[32][64];
    int r0 = blockIdx.x * 64;
    int c0 = blockIdx.y * 64;
    int t = threadIdx.x;
    int tx = t & 15, ty = t >> 4;
    float acc[4][4];
    #pragma unroll
    for (int i = 0; i < 4; ++i)
        #pragma unroll
        for (int j = 0; j < 4; ++j) acc[i][j] = 0.f;

    for (int k0 = 0; k0 < K; k0 += 32) {
        int j = t * 4;
        #pragma unroll
        for (int p = 0; p < 2; ++p) {
            int row = j >> 5, kk = j & 31;
            v4f v = {0.f, 0.f, 0.f, 0.f};
            int gr = r0 + row;
            if (gr < Nrows) {
                const v4f* ap = (const v4f*)&A[gr * K + k0 + kk];
                v = NTA ? __builtin_nontemporal_load(ap) : *ap;
            }
            As[kk + 0][row] = v.x; As[kk + 1][row] = v.y;
            As[kk + 2][row] = v.z; As[kk + 3][row] = v.w;
            j += 1024;
        }
        j = t * 4;
        #pragma unroll
        for (int p = 0; p < 2; ++p) {
            int row = j >> 6, col = j & 63;
            float4 w = make_float4(0.f, 0.f, 0.f, 0.f);
            if (c0 + col < NC) w = *(const float4*)&B[(k0 + row) * NC + c0 + col];
            *(float4*)&Bs[row][col] = w;
            j += 1024;
        }
        __syncthreads();
        #pragma unroll
        for (int kk = 0; kk < 32; ++kk) {
            float4 a = *(const float4*)&As[kk][ty * 4];
            float4 b = *(const float4*)&Bs[kk][tx * 4];
            acc[0][0] = fmaf(a.x, b.x, acc[0][0]); acc[0][1] = fmaf(a.x, b.y, acc[0][1]);
            acc[0][2] = fmaf(a.x, b.z, acc[0][2]); acc[0][3] = fmaf(a.x, b.w, acc[0][3]);
            acc[1][0] = fmaf(a.y, b.x, acc[1][0]); acc[1][1] = fmaf(a.y, b.y, acc[1][1]);
            acc[1][2] = fmaf(a.y, b.z, acc[1][2]); acc[1][3] = fmaf(a.y, b.w, acc[1][3]);
            acc[2][0] = fmaf(a.z, b.x, acc[2][0]); acc[2][1] = fmaf(a.z, b.y, acc[2][1]);
            acc[2][2] = fmaf(a.z, b.z, acc[2][2]); acc[2][3] = fmaf(a.z, b.w, acc[2][3]);
            acc[3][0] = fmaf(a.w, b.x, acc[3][0]); acc[3][1] = fmaf(a.w, b.y, acc[3][1]);
            acc[3][2] = fmaf(a.w, b.z, acc[3][2]); acc[3][3] = fmaf(a.w, b.w, acc[3][3]);
        }
        __syncthreads();
    }
    #pragma unroll
    for (int i = 0; i < 4; ++i) {
        int gr = r0 + ty * 4 + i;
        if (gr < Nrows && (c0 + tx * 4) < NC) {
            float4 o = make_float4(acc[i][0], acc[i][1], acc[i][2], acc[i][3]);
            *(float4*)&C[gr * NC + c0 + tx * 4] = o;
        }
    }
}

// ---------------- alpha for head-sliced features (layers 0/1) ----------------
__global__ __launch_bounds__(256) void k_alpha_hs(const float* __restrict__ h, const float* __restrict__ a_s,
                                                  const float* __restrict__ a_d,
                                                  float* __restrict__ asrc, float* __restrict__ adst) {
    int t = threadIdx.x;
    int lane = t & 63;
    int n = (blockIdx.x * 256 + t) >> 6;
    if (n >= NNODE) return;
    float v = h[n * 64 + lane];
    float s = v * a_s[lane];
    float d = v * a_d[lane];
    s += __shfl_xor(s, 1); s += __shfl_xor(s, 2); s += __shfl_xor(s, 4);
    d += __shfl_xor(d, 1); d += __shfl_xor(d, 2); d += __shfl_xor(d, 4);
    if ((lane & 7) == 0) {
        asrc[n * 8 + (lane >> 3)] = s;
        adst[n * 8 + (lane >> 3)] = d;
    }
}

// ---------------- aggregation for layers 0/1 (64 features), pipelined ----------------
__global__ __launch_bounds__(256) void k_agg64(const float* __restrict__ h, const float* __restrict__ asrc,
                                               const float* __restrict__ adst, const int* __restrict__ rowptr,
                                               const int* __restrict__ csr, const float* __restrict__ bias,
                                               float* __restrict__ out, int doElu) {
    int t = threadIdx.x;
    int lane = t & 63;
    int n = (blockIdx.x * 256 + t) >> 6;
    if (n >= NNODE) return;
    int start = rfl(rowptr[n]);
    int end   = rfl(rowptr[n + 1]);
    int h_lo = lane & 7;
    int h_hi = lane >> 3;
    float adst_lo = adst[n * 8 + h_lo];
    // pass 1: per-head max, 8 edges x 8 heads per iter, 2 loads in flight
    float m = -1e30f;
    for (int i = start + (lane >> 3); i < end; i += 16) {
        int s0 = csr[i];
        int i2 = i + 8;
        int s1 = (i2 < end) ? csr[i2] : s0;
        float a0 = asrc[s0 * 8 + h_lo];
        float a1 = asrc[s1 * 8 + h_lo];
        m = fmaxf(m, lrelu(a0 + adst_lo));
        if (i2 < end) m = fmaxf(m, lrelu(a1 + adst_lo));
    }
    m = fmaxf(m, __shfl_xor(m, 8));
    m = fmaxf(m, __shfl_xor(m, 16));
    m = fmaxf(m, __shfl_xor(m, 32));
    float m_hi    = __shfl(m, h_hi);
    float adst_hi = __shfl(adst_lo, h_hi);
    // pass 2: edge-serial, depth-3 pipeline (sA/sB/sC in SGPRs, 2 gathers in flight)
    float acc = 0.f, ssum = 0.f;
    int i1 = min(start + 1, end - 1);
    int i2p = min(start + 2, end - 1);
    int sA = rfl(csr[start]);
    int sB = rfl(csr[i1]);
    int sC = rfl(csr[i2p]);
    float vA = h[sA * 64 + lane];
    float aA = asrc[sA * 8 + h_hi];
    float vB = h[sB * 64 + lane];
    float aB = asrc[sB * 8 + h_hi];
    for (int i = start; i < end; ++i) {
        int sN = (i + 3 < end) ? rfl(csr[i + 3]) : sC;
        float e = lrelu(aA + adst_hi);
        float ex = __expf(e - m_hi);
        ssum += ex;
        acc = fmaf(ex, vA, acc);
        vA = vB; aA = aB;
        vB = h[sC * 64 + lane];
        aB = asrc[sC * 8 + h_hi];
        sC = sN;
    }
    float o = acc / (ssum + 1e-16f) + bias[lane];
    if (doElu) o = (o > 0.f) ? o : expm1f(o);
    out[n * 64 + lane] = o;
}

// ---------------- layer-2 weight precompute ----------------
__global__ __launch_bounds__(256) void k_prep_w2(const float* __restrict__ W2, const float* __restrict__ as2,
                                                 const float* __restrict__ ad2,
                                                 float* __restrict__ wa, float* __restrict__ w2r) {
    int idx = blockIdx.x * 256 + threadIdx.x;
    if (idx < 1024) {
        int which = idx >> 9;
        int hh = (idx >> 6) & 7, k = idx & 63;
        const float* a = which ? ad2 : as2;
        float s = 0.f;
        #pragma unroll 8
        for (int c = 0; c < NCLS; ++c) s += W2[k * 320 + hh * 40 + c] * a[hh * 40 + c];
        wa[idx] = s;
    }
    for (int j2 = idx; j2 < 512 * NCLS; j2 += gridDim.x * 256) {
        int rc = j2 / NCLS, c = j2 - rc * NCLS;
        int hh = rc >> 6, k = rc & 63;
        w2r[j2] = W2[k * 320 + hh * 40 + c] * 0.125f;
    }
}

// ---------------- alpha for layer 2 ----------------
__global__ __launch_bounds__(256) void k_alpha2(const float* __restrict__ h, const float* __restrict__ wa,
                                                float* __restrict__ asrc, float* __restrict__ adst) {
    __shared__ float ws[1024];
    int t = threadIdx.x;
    for (int j = t; j < 1024; j += 256) ws[j] = wa[j];
    __syncthreads();
    int lane = t & 63;
    int n = (blockIdx.x * 256 + t) >> 6;
    if (n >= NNODE) return;
    float v = h[n * 64 + lane];
    #pragma unroll
    for (int hh = 0; hh < 8; ++hh) {
        float s = v * ws[hh * 64 + lane];
        float d = v * ws[512 + hh * 64 + lane];
        #pragma unroll
        for (int mk = 32; mk; mk >>= 1) { s += __shfl_xor(s, mk); d += __shfl_xor(d, mk); }
        if (lane == 0) { asrc[n * 8 + hh] = s; adst[n * 8 + hh] = d; }
    }
}

// ---------------- layer-2 aggregation, pipelined, nt g-store ----------------
__global__ __launch_bounds__(256) void k_agg512(const float* __restrict__ h, const float* __restrict__ asrc,
                                                const float* __restrict__ adst, const int* __restrict__ rowptr,
                                                const int* __restrict__ csr, float* __restrict__ g) {
    int t = threadIdx.x;
    int lane = t & 63;
    int n = (blockIdx.x * 256 + t) >> 6;
    if (n >= NNODE) return;
    int start = rfl(rowptr[n]);
    int end   = rfl(rowptr[n + 1]);
    int h_lo = lane & 7;
    float adst_lo = adst[n * 8 + h_lo];
    // pass 1: per-head max, 2 loads in flight
    float m = -1e30f;
    for (int i = start + (lane >> 3); i < end; i += 16) {
        int s0 = csr[i];
        int i2 = i + 8;
        int s1 = (i2 < end) ? csr[i2] : s0;
        float a0 = asrc[s0 * 8 + h_lo];
        float a1 = asrc[s1 * 8 + h_lo];
        m = fmaxf(m, lrelu(a0 + adst_lo));
        if (i2 < end) m = fmaxf(m, lrelu(a1 + adst_lo));
    }
    m = fmaxf(m, __shfl_xor(m, 8));
    m = fmaxf(m, __shfl_xor(m, 16));
    m = fmaxf(m, __shfl_xor(m, 32));
    // pass 2: edge-serial, depth-3 pipeline
    float acc[8];
    #pragma unroll
    for (int hh = 0; hh < 8; ++hh) acc[hh] = 0.f;
    float ssum = 0.f;
    int i1 = min(start + 1, end - 1);
    int i2p = min(start + 2, end - 1);
    int sA = rfl(csr[start]);
    int sB = rfl(csr[i1]);
    int sC = rfl(csr[i2p]);
    float vA = h[sA * 64 + lane];
    float aA = asrc[sA * 8 + h_lo];
    float vB = h[sB * 64 + lane];
    float aB = asrc[sB * 8 + h_lo];
    for (int i = start; i < end; ++i) {
        int sN = (i + 3 < end) ? rfl(csr[i + 3]) : sC;
        float e = lrelu(aA + adst_lo);
        float ex = __expf(e - m);
        ssum += ex;
        #pragma unroll
        for (int hh = 0; hh < 8; ++hh) {
            float exh = __shfl(ex, hh);
            acc[hh] = fmaf(exh, vA, acc[hh]);
        }
        vA = vB; aA = aB;
        vB = h[sC * 64 + lane];
        aB = asrc[sC * 8 + h_lo];
        sC = sN;
    }
    #pragma unroll
    for (int hh = 0; hh < 8; ++hh) {
        float sh = __shfl(ssum, hh);
        // nt store: g is streamed once into the final GEMM; keep h1 in L3.
        __builtin_nontemporal_store(acc[hh] / (sh + 1e-16f), &g[n * 512 + hh * 64 + lane]);
    }
}

// ---------------- final: bias + log_softmax in place on d_out [N,40] ----------------
__global__ __launch_bounds__(256) void k_logsm(float* __restrict__ out, const float* __restrict__ b2) {
    int t = threadIdx.x;
    int lane = t & 63;
    int n = (blockIdx.x * 256 + t) >> 6;
    if (n >= NNODE) return;
    float v = (lane < NCLS) ? out[n * NCLS + lane] + b2[lane] : -1e30f;
    float m = v;
    #pragma unroll
    for (int mk = 32; mk; mk >>= 1) m = fmaxf(m, __shfl_xor(m, mk));
    float ex = (lane < NCLS) ? __expf(v - m) : 0.f;
    float s = ex;
    #pragma unroll
    for (int mk = 32; mk; mk >>= 1) s += __shfl_xor(s, mk);
    float r = v - m - logf(s);
    if (lane < NCLS) out[n * NCLS + lane] = r;
}

// ---------------- launch ----------------
extern "C" void kernel_launch(void* const* d_in, const int* in_sizes, int n_in,
                              void* d_out, int out_size, void* d_ws, size_t ws_size,
                              hipStream_t stream) {
    (void)in_sizes; (void)n_in; (void)out_size; (void)ws_size;
    const float* x   = (const float*)d_in[0];
    const int*   ei  = (const int*)d_in[1];
    const float* W0  = (const float*)d_in[2];
    const float* as0 = (const float*)d_in[3];
    const float* ad0 = (const float*)d_in[4];
    const float* b0  = (const float*)d_in[5];
    const float* W1  = (const float*)d_in[6];
    const float* as1 = (const float*)d_in[7];
    const float* ad1 = (const float*)d_in[8];
    const float* b1  = (const float*)d_in[9];
    const float* W2  = (const float*)d_in[10];
    const float* as2 = (const float*)d_in[11];
    const float* ad2 = (const float*)d_in[12];
    const float* b2  = (const float*)d_in[13];
    float* outp = (float*)d_out;

    size_t off = 0;
    auto alloc = [&](size_t bytes) -> void* {
        void* p = (char*)d_ws + off;
        off += (bytes + 255) & ~(size_t)255;
        return p;
    };
    int*   deg    = (int*)alloc((size_t)NNODE * 4);
    int*   fill   = (int*)alloc((size_t)NNODE * 4);
    int*   rowptr = (int*)alloc((size_t)(NNODE + 1) * 4);
    int*   bsum   = (int*)alloc(256 * 4);
    int*   csr    = (int*)alloc((size_t)ETOT * 4);
    float* asrc   = (float*)alloc((size_t)NNODE * 8 * 4);
    float* adst   = (float*)alloc((size_t)NNODE * 8 * 4);
    float* bufA   = (float*)alloc((size_t)NNODE * 64 * 4);
    float* bufB   = (float*)alloc((size_t)NNODE * 64 * 4);
    float* wa     = (float*)alloc(1024 * 4);
    float* w2r    = (float*)alloc((size_t)512 * NCLS * 4);
    float* g      = (float*)alloc((size_t)NNODE * 512 * 4);

    const int nb = (NNODE + 1023) / 1024;
    const int egrid = (ETOT + 255) / 256;
    const int ngrid = (NNODE + 255) / 256;
    const int wgrid = NNODE / 4;
    const int rtiles = (NNODE + 63) / 64;

    hipMemsetAsync(deg, 0, (size_t)NNODE * 4, stream);
    hipMemsetAsync(fill, 0, (size_t)NNODE * 4, stream);
    k_hist<<<egrid, 256, 0, stream>>>(ei, deg);
    k_scan1<<<nb, 256, 0, stream>>>(deg, rowptr, bsum);
    k_scan2<<<1, 256, 0, stream>>>(bsum, nb);
    k_scan3<<<ngrid, 256, 0, stream>>>(rowptr, bsum);
    k_scatter<<<egrid, 256, 0, stream>>>(ei, rowptr, fill, csr);

    k_gemm<true><<<dim3(rtiles, 1), 256, 0, stream>>>(x, W0, bufA, NNODE, FIN, HID);
    k_alpha_hs<<<wgrid, 256, 0, stream>>>(bufA, as0, ad0, asrc, adst);
    k_agg64<<<wgrid, 256, 0, stream>>>(bufA, asrc, adst, rowptr, csr, b0, bufB, 1);

    k_gemm<false><<<dim3(rtiles, 1), 256, 0, stream>>>(bufB, W1, bufA, NNODE, HID, HID);
    k_alpha_hs<<<wgrid, 256, 0, stream>>>(bufA, as1, ad1, asrc, adst);
    k_agg64<<<wgrid, 256, 0, stream>>>(bufA, asrc, adst, rowptr, csr, b1, bufB, 1);

    k_prep_w2<<<80, 256, 0, stream>>>(W2, as2, ad2, wa, w2r);
    k_alpha2<<<wgrid, 256, 0, stream>>>(bufB, wa, asrc, adst);
    k_agg512<<<wgrid, 256, 0, stream>>>(bufB, asrc, adst, rowptr, csr, g);
    k_gemm<true><<<dim3(rtiles, 1), 256, 0, stream>>>(g, w2r, outp, NNODE, 512, NCLS);
    k_logsm<<<wgrid, 256, 0, stream>>>(outp, b2);
}

// Round 7
// 1118.683 us; speedup vs baseline: 1.1079x; 1.1079x over previous
//
#include <hip/hip_runtime.h>

// GAT 3-layer forward, MI355X. Round 5 re-resubmit (rounds 5 and 6 never acquired a GPU):
//  - CSR-by-dst on device (hist + scan + scatter), no float atomics.
//  - Aggregation is latency-concurrency bound (r4: 2.6 TB/s eff, VALUBusy 55%,
//    ~2 gathers in flight ~= 3.3 TB/s cap). THIS ROUND:
//    (a) no-max softmax (mathematically identical ratios; removes pass-1's
//        ~110MB/kernel random asrc re-gather + shfl reduces),
//    (b) chunked ping-pong pipeline: 4 h-row gathers + 4 alpha gathers in
//        flight during compute,
//    (c) bias+log_softmax fused into final GEMM epilogue (drop k_logsm).
//  - layer2: aggregate h1 per head (g=[N,8,64]) then GEMM with rearranged W2.

#define NNODE 100000
#define NEDGE 1600000
#define ETOT  (NNODE + NEDGE)   // 1,700,000 incl self-loops
#define FIN   512
#define HID   64
#define NHEAD 8
#define NCLS  40

typedef float v4f __attribute__((ext_vector_type(4)));

static __device__ __forceinline__ float lrelu(float x) { return x > 0.f ? x : 0.2f * x; }
static __device__ __forceinline__ int rfl(int v) { return __builtin_amdgcn_readfirstlane(v); }

// ---------------- CSR build ----------------
__global__ __launch_bounds__(256) void k_hist(const int* __restrict__ ei, int* __restrict__ deg) {
    int e = blockIdx.x * 256 + threadIdx.x;
    if (e >= ETOT) return;
    int dst = (e < NEDGE) ? ei[NEDGE + e] : (e - NEDGE);
    atomicAdd(&deg[dst], 1);
}

__global__ __launch_bounds__(256) void k_scan1(const int* __restrict__ deg, int* __restrict__ rowptr,
                                               int* __restrict__ bsum) {
    __shared__ int sm[256];
    int b = blockIdx.x, t = threadIdx.x;
    int base = b * 1024 + t * 4;
    int v0=0,v1=0,v2=0,v3=0;
    if (base + 0 < NNODE) v0 = deg[base + 0];
    if (base + 1 < NNODE) v1 = deg[base + 1];
    if (base + 2 < NNODE) v2 = deg[base + 2];
    if (base + 3 < NNODE) v3 = deg[base + 3];
    int tsum = v0 + v1 + v2 + v3;
    sm[t] = tsum;
    __syncthreads();
    int val = tsum;
    for (int off = 1; off < 256; off <<= 1) {
        int y = (t >= off) ? sm[t - off] : 0;
        __syncthreads();
        val += y;
        sm[t] = val;
        __syncthreads();
    }
    int ex = val - tsum;
    if (base + 0 < NNODE) rowptr[base + 0] = ex;
    if (base + 1 < NNODE) rowptr[base + 1] = ex + v0;
    if (base + 2 < NNODE) rowptr[base + 2] = ex + v0 + v1;
    if (base + 3 < NNODE) rowptr[base + 3] = ex + v0 + v1 + v2;
    if (t == 255) bsum[b] = val;
}

__global__ __launch_bounds__(256) void k_scan2(int* __restrict__ bsum, int nb) {
    __shared__ int sm[256];
    int t = threadIdx.x;
    int v = (t < nb) ? bsum[t] : 0;
    sm[t] = v;
    __syncthreads();
    int val = v;
    for (int off = 1; off < 256; off <<= 1) {
        int y = (t >= off) ? sm[t - off] : 0;
        __syncthreads();
        val += y;
        sm[t] = val;
        __syncthreads();
    }
    if (t < nb) bsum[t] = val - v;
}

__global__ __launch_bounds__(256) void k_scan3(int* __restrict__ rowptr, const int* __restrict__ bsum) {
    int i = blockIdx.x * 256 + threadIdx.x;
    if (i < NNODE) rowptr[i] += bsum[i >> 10];
    if (i == 0) rowptr[NNODE] = ETOT;
}

__global__ __launch_bounds__(256) void k_scatter(const int* __restrict__ ei, const int* __restrict__ rowptr,
                                                 int* __restrict__ fill, int* __restrict__ csr) {
    int e = blockIdx.x * 256 + threadIdx.x;
    if (e >= ETOT) return;
    int s, d;
    if (e < NEDGE) { s = ei[e]; d = ei[NEDGE + e]; } else { s = e - NEDGE; d = s; }
    int pos = rowptr[d] + atomicAdd(&fill[d], 1);
    csr[pos] = s;
}

// ---------------- generic fp32 GEMM: C[NrowsxNC] = A[NrowsxK] @ B[KxNC] ----------------
// NTA: non-temporal A loads (A streamed once). FUSE: bias + log_softmax epilogue (NC==40).
template <bool NTA, bool FUSE>
__global__ __launch_bounds__(256) void k_gemm(const float* __restrict__ A, const float* __restrict__ B,
                                              float* __restrict__ C, int Nrows, int K, int NC,
                                              const float* __restrict__ bias2) {
    __shared__ float As[32][68];
    __shared__ float Bs[32][64];
    int r0 = blockIdx.x * 64;
    int c0 = blockIdx.y * 64;
    int t = threadIdx.x;
    int tx = t & 15, ty = t >> 4;
    float acc[4][4];
    #pragma unroll
    for (int i = 0; i < 4; ++i)
        #pragma unroll
        for (int j = 0; j < 4; ++j) acc[i][j] = 0.f;

    for (int k0 = 0; k0 < K; k0 += 32) {
        int j = t * 4;
        #pragma unroll
        for (int p = 0; p < 2; ++p) {
            int row = j >> 5, kk = j & 31;
            v4f v = {0.f, 0.f, 0.f, 0.f};
            int gr = r0 + row;
            if (gr < Nrows) {
                const v4f* ap = (const v4f*)&A[gr * K + k0 + kk];
                v = NTA ? __builtin_nontemporal_load(ap) : *ap;
            }
            As[kk + 0][row] = v.x; As[kk + 1][row] = v.y;
            As[kk + 2][row] = v.z; As[kk + 3][row] = v.w;
            j += 1024;
        }
        j = t * 4;
        #pragma unroll
        for (int p = 0; p < 2; ++p) {
            int row = j >> 6, col = j & 63;
            float4 w = make_float4(0.f, 0.f, 0.f, 0.f);
            if (c0 + col < NC) w = *(const float4*)&B[(k0 + row) * NC + c0 + col];
            *(float4*)&Bs[row][col] = w;
            j += 1024;
        }
        __syncthreads();
        #pragma unroll
        for (int kk = 0; kk < 32; ++kk) {
            float4 a = *(const float4*)&As[kk][ty * 4];
            float4 b = *(const float4*)&Bs[kk][tx * 4];
            acc[0][0] = fmaf(a.x, b.x, acc[0][0]); acc[0][1] = fmaf(a.x, b.y, acc[0][1]);
            acc[0][2] = fmaf(a.x, b.z, acc[0][2]); acc[0][3] = fmaf(a.x, b.w, acc[0][3]);
            acc[1][0] = fmaf(a.y, b.x, acc[1][0]); acc[1][1] = fmaf(a.y, b.y, acc[1][1]);
            acc[1][2] = fmaf(a.y, b.z, acc[1][2]); acc[1][3] = fmaf(a.y, b.w, acc[1][3]);
            acc[2][0] = fmaf(a.z, b.x, acc[2][0]); acc[2][1] = fmaf(a.z, b.y, acc[2][1]);
            acc[2][2] = fmaf(a.z, b.z, acc[2][2]); acc[2][3] = fmaf(a.z, b.w, acc[2][3]);
            acc[3][0] = fmaf(a.w, b.x, acc[3][0]); acc[3][1] = fmaf(a.w, b.y, acc[3][1]);
            acc[3][2] = fmaf(a.w, b.z, acc[3][2]); acc[3][3] = fmaf(a.w, b.w, acc[3][3]);
        }
        __syncthreads();
    }

    if constexpr (FUSE) {
        // bias + log_softmax over the 40 cols of each row (NC==40, single col-tile).
        __shared__ float smO[64][41];
        __shared__ float smM[64], smL[64];
        #pragma unroll
        for (int i = 0; i < 4; ++i) {
            int rl = ty * 4 + i;
            #pragma unroll
            for (int j = 0; j < 4; ++j) {
                int c = tx * 4 + j;
                if (c < NCLS) smO[rl][c] = acc[i][j] + bias2[c];
            }
        }
        __syncthreads();
        if (t < 64) {
            float mx = -1e30f;
            #pragma unroll 8
            for (int c = 0; c < NCLS; ++c) mx = fmaxf(mx, smO[t][c]);
            float se = 0.f;
            #pragma unroll 8
            for (int c = 0; c < NCLS; ++c) se += __expf(smO[t][c] - mx);
            smM[t] = mx;
            smL[t] = logf(se);
        }
        __syncthreads();
        #pragma unroll
        for (int i = 0; i < 4; ++i) {
            int rl = ty * 4 + i;
            int gr = r0 + rl;
            if (gr < Nrows) {
                float mm = smM[rl], ll = smL[rl];
                #pragma unroll
                for (int j = 0; j < 4; ++j) {
                    int c = tx * 4 + j;
                    if (c < NCLS) C[gr * NCLS + c] = acc[i][j] + bias2[c] - mm - ll;
                }
            }
        }
    } else {
        #pragma unroll
        for (int i = 0; i < 4; ++i) {
            int gr = r0 + ty * 4 + i;
            if (gr < Nrows && (c0 + tx * 4) < NC) {
                float4 o = make_float4(acc[i][0], acc[i][1], acc[i][2], acc[i][3]);
                *(float4*)&C[gr * NC + c0 + tx * 4] = o;
            }
        }
    }
}

// ---------------- alpha for head-sliced features (layers 0/1) ----------------
__global__ __launch_bounds__(256) void k_alpha_hs(const float* __restrict__ h, const float* __restrict__ a_s,
                                                  const float* __restrict__ a_d,
                                                  float* __restrict__ asrc, float* __restrict__ adst) {
    int t = threadIdx.x;
    int lane = t & 63;
    int n = (blockIdx.x * 256 + t) >> 6;
    if (n >= NNODE) return;
    float v = h[n * 64 + lane];
    float s = v * a_s[lane];
    float d = v * a_d[lane];
    s += __shfl_xor(s, 1); s += __shfl_xor(s, 2); s += __shfl_xor(s, 4);
    d += __shfl_xor(d, 1); d += __shfl_xor(d, 2); d += __shfl_xor(d, 4);
    if ((lane & 7) == 0) {
        asrc[n * 8 + (lane >> 3)] = s;
        adst[n * 8 + (lane >> 3)] = d;
    }
}

// ---- pipelined index/value window helpers (macros keep all names static) ----
#define LD_IDX(S0,S1,S2,S3,BASE)                         \
    S0 = rfl(csr[min((BASE) + 0, e1)]);                  \
    S1 = rfl(csr[min((BASE) + 1, e1)]);                  \
    S2 = rfl(csr[min((BASE) + 2, e1)]);                  \
    S3 = rfl(csr[min((BASE) + 3, e1)]);

#define LD_VAL(S0,S1,S2,S3,V0,V1,V2,V3,A0,A1,A2,A3)     \
    V0 = h[S0 * 64 + lane];  A0 = asrc[S0 * 8 + hh];    \
    V1 = h[S1 * 64 + lane];  A1 = asrc[S1 * 8 + hh];    \
    V2 = h[S2 * 64 + lane];  A2 = asrc[S2 * 8 + hh];    \
    V3 = h[S3 * 64 + lane];  A3 = asrc[S3 * 8 + hh];

// ---------------- aggregation layers 0/1 (64 feats): no-max softmax, deep pipeline ----
__global__ __launch_bounds__(256) void k_agg64(const float* __restrict__ h, const float* __restrict__ asrc,
                                               const float* __restrict__ adst, const int* __restrict__ rowptr,
                                               const int* __restrict__ csr, const float* __restrict__ bias,
                                               float* __restrict__ out, int doElu) {
    int t = threadIdx.x;
    int lane = t & 63;
    int n = (blockIdx.x * 256 + t) >> 6;
    if (n >= NNODE) return;
    int start = rfl(rowptr[n]);
    int end   = rfl(rowptr[n + 1]);
    int e1 = end - 1;
    int hh = lane >> 3;                 // head in feature layout (lane = h*8+c)
    float ad = adst[n * 8 + hh];

    int   sA0,sA1,sA2,sA3, sB0,sB1,sB2,sB3;
    float vA0,vA1,vA2,vA3, aA0,aA1,aA2,aA3;
    float vB0,vB1,vB2,vB3, aB0,aB1,aB2,aB3;
    LD_IDX(sA0,sA1,sA2,sA3, start)
    LD_VAL(sA0,sA1,sA2,sA3, vA0,vA1,vA2,vA3, aA0,aA1,aA2,aA3)
    LD_IDX(sB0,sB1,sB2,sB3, start + 4)
    LD_VAL(sB0,sB1,sB2,sB3, vB0,vB1,vB2,vB3, aB0,aB1,aB2,aB3)

    float acc = 0.f, ssum = 0.f;
    #define EDGE64(AV,AA,COND)                                        \
        if (COND) {                                                   \
            float x_ = __expf(fminf(lrelu((AA) + ad), 80.f));         \
            ssum += x_;                                               \
            acc = fmaf(x_, (AV), acc);                                \
        }
    for (int base = start; base < end; base += 8) {
        EDGE64(vA0, aA0, true)
        EDGE64(vA1, aA1, base + 1 < end)
        EDGE64(vA2, aA2, base + 2 < end)
        EDGE64(vA3, aA3, base + 3 < end)
        if (base + 8 < end) {
            LD_IDX(sA0,sA1,sA2,sA3, base + 8)
            LD_VAL(sA0,sA1,sA2,sA3, vA0,vA1,vA2,vA3, aA0,aA1,aA2,aA3)
        }
        EDGE64(vB0, aB0, base + 4 < end)
        EDGE64(vB1, aB1, base + 5 < end)
        EDGE64(vB2, aB2, base + 6 < end)
        EDGE64(vB3, aB3, base + 7 < end)
        if (base + 12 < end) {
            LD_IDX(sB0,sB1,sB2,sB3, base + 12)
            LD_VAL(sB0,sB1,sB2,sB3, vB0,vB1,vB2,vB3, aB0,aB1,aB2,aB3)
        }
    }
    #undef EDGE64
    float o = acc / (ssum + 1e-16f) + bias[lane];
    if (doElu) o = (o > 0.f) ? o : expm1f(o);
    out[n * 64 + lane] = o;
}

// ---------------- layer-2 weight precompute ----------------
__global__ __launch_bounds__(256) void k_prep_w2(const float* __restrict__ W2, const float* __restrict__ as2,
                                                 const float* __restrict__ ad2,
                                                 float* __restrict__ wa, float* __restrict__ w2r) {
    int idx = blockIdx.x * 256 + threadIdx.x;
    if (idx < 1024) {
        int which = idx >> 9;
        int hh = (idx >> 6) & 7, k = idx & 63;
        const float* a = which ? ad2 : as2;
        float s = 0.f;
        #pragma unroll 8
        for (int c = 0; c < NCLS; ++c) s += W2[k * 320 + hh * 40 + c] * a[hh * 40 + c];
        wa[idx] = s;
    }
    for (int j2 = idx; j2 < 512 * NCLS; j2 += gridDim.x * 256) {
        int rc = j2 / NCLS, c = j2 - rc * NCLS;
        int hh = rc >> 6, k = rc & 63;
        w2r[j2] = W2[k * 320 + hh * 40 + c] * 0.125f;
    }
}

// ---------------- alpha for layer 2 ----------------
__global__ __launch_bounds__(256) void k_alpha2(const float* __restrict__ h, const float* __restrict__ wa,
                                                float* __restrict__ asrc, float* __restrict__ adst) {
    __shared__ float ws[1024];
    int t = threadIdx.x;
    for (int j = t; j < 1024; j += 256) ws[j] = wa[j];
    __syncthreads();
    int lane = t & 63;
    int n = (blockIdx.x * 256 + t) >> 6;
    if (n >= NNODE) return;
    float v = h[n * 64 + lane];
    #pragma unroll
    for (int hh = 0; hh < 8; ++hh) {
        float s = v * ws[hh * 64 + lane];
        float d = v * ws[512 + hh * 64 + lane];
        #pragma unroll
        for (int mk = 32; mk; mk >>= 1) { s += __shfl_xor(s, mk); d += __shfl_xor(d, mk); }
        if (lane == 0) { asrc[n * 8 + hh] = s; adst[n * 8 + hh] = d; }
    }
}

// ---------------- layer-2 aggregation: no-max softmax, deep pipeline, nt g-store ----
__global__ __launch_bounds__(256) void k_agg512(const float* __restrict__ h, const float* __restrict__ asrc,
                                                const float* __restrict__ adst, const int* __restrict__ rowptr,
                                                const int* __restrict__ csr, float* __restrict__ g) {
    int t = threadIdx.x;
    int lane = t & 63;
    int n = (blockIdx.x * 256 + t) >> 6;
    if (n >= NNODE) return;
    int start = rfl(rowptr[n]);
    int end   = rfl(rowptr[n + 1]);
    int e1 = end - 1;
    int hh = lane & 7;                  // head owned by this lane for alpha
    float ad = adst[n * 8 + hh];

    int   sA0,sA1,sA2,sA3, sB0,sB1,sB2,sB3;
    float vA0,vA1,vA2,vA3, aA0,aA1,aA2,aA3;
    float vB0,vB1,vB2,vB3, aB0,aB1,aB2,aB3;
    LD_IDX(sA0,sA1,sA2,sA3, start)
    LD_VAL(sA0,sA1,sA2,sA3, vA0,vA1,vA2,vA3, aA0,aA1,aA2,aA3)
    LD_IDX(sB0,sB1,sB2,sB3, start + 4)
    LD_VAL(sB0,sB1,sB2,sB3, vB0,vB1,vB2,vB3, aB0,aB1,aB2,aB3)

    float acc[8];
    #pragma unroll
    for (int k = 0; k < 8; ++k) acc[k] = 0.f;
    float ssum = 0.f;

    #define EDGE512(AV,AA,COND)                                       \
        if (COND) {                                                   \
            float x_ = __expf(fminf(lrelu((AA) + ad), 80.f));         \
            ssum += x_;                                               \
            float x0_ = __shfl(x_, 0); acc[0] = fmaf(x0_, (AV), acc[0]); \
            float x1_ = __shfl(x_, 1); acc[1] = fmaf(x1_, (AV), acc[1]); \
            float x2_ = __shfl(x_, 2); acc[2] = fmaf(x2_, (AV), acc[2]); \
            float x3_ = __shfl(x_, 3); acc[3] = fmaf(x3_, (AV), acc[3]); \
            float x4_ = __shfl(x_, 4); acc[4] = fmaf(x4_, (AV), acc[4]); \
            float x5_ = __shfl(x_, 5); acc[5] = fmaf(x5_, (AV), acc[5]); \
            float x6_ = __shfl(x_, 6); acc[6] = fmaf(x6_, (AV), acc[6]); \
            float x7_ = __shfl(x_, 7); acc[7] = fmaf(x7_, (AV), acc[7]); \
        }
    for (int base = start; base < end; base += 8) {
        EDGE512(vA0, aA0, true)
        EDGE512(vA1, aA1, base + 1 < end)
        EDGE512(vA2, aA2, base + 2 < end)
        EDGE512(vA3, aA3, base + 3 < end)
        if (base + 8 < end) {
            LD_IDX(sA0,sA1,sA2,sA3, base + 8)
            LD_VAL(sA0,sA1,sA2,sA3, vA0,vA1,vA2,vA3, aA0,aA1,aA2,aA3)
        }
        EDGE512(vB0, aB0, base + 4 < end)
        EDGE512(vB1, aB1, base + 5 < end)
        EDGE512(vB2, aB2, base + 6 < end)
        EDGE512(vB3, aB3, base + 7 < end)
        if (base + 12 < end) {
            LD_IDX(sB0,sB1,sB2,sB3, base + 12)
            LD_VAL(sB0,sB1,sB2,sB3, vB0,vB1,vB2,vB3, aB0,aB1,aB2,aB3)
        }
    }
    #undef EDGE512

    #pragma unroll
    for (int k = 0; k < 8; ++k) {
        float sh = __shfl(ssum, k);
        __builtin_nontemporal_store(acc[k] / (sh + 1e-16f), &g[n * 512 + k * 64 + lane]);
    }
}

// ---------------- launch ----------------
extern "C" void kernel_launch(void* const* d_in, const int* in_sizes, int n_in,
                              void* d_out, int out_size, void* d_ws, size_t ws_size,
                              hipStream_t stream) {
    (void)in_sizes; (void)n_in; (void)out_size; (void)ws_size;
    const float* x   = (const float*)d_in[0];
    const int*   ei  = (const int*)d_in[1];
    const float* W0  = (const float*)d_in[2];
    const float* as0 = (const float*)d_in[3];
    const float* ad0 = (const float*)d_in[4];
    const float* b0  = (const float*)d_in[5];
    const float* W1  = (const float*)d_in[6];
    const float* as1 = (const float*)d_in[7];
    const float* ad1 = (const float*)d_in[8];
    const float* b1  = (const float*)d_in[9];
    const float* W2  = (const float*)d_in[10];
    const float* as2 = (const float*)d_in[11];
    const float* ad2 = (const float*)d_in[12];
    const float* b2  = (const float*)d_in[13];
    float* outp = (float*)d_out;

    size_t off = 0;
    auto alloc = [&](size_t bytes) -> void* {
        void* p = (char*)d_ws + off;
        off += (bytes + 255) & ~(size_t)255;
        return p;
    };
    int*   deg    = (int*)alloc((size_t)NNODE * 4);
    int*   fill   = (int*)alloc((size_t)NNODE * 4);
    int*   rowptr = (int*)alloc((size_t)(NNODE + 1) * 4);
    int*   bsum   = (int*)alloc(256 * 4);
    int*   csr    = (int*)alloc((size_t)ETOT * 4);
    float* asrc   = (float*)alloc((size_t)NNODE * 8 * 4);
    float* adst   = (float*)alloc((size_t)NNODE * 8 * 4);
    float* bufA   = (float*)alloc((size_t)NNODE * 64 * 4);
    float* bufB   = (float*)alloc((size_t)NNODE * 64 * 4);
    float* wa     = (float*)alloc(1024 * 4);
    float* w2r    = (float*)alloc((size_t)512 * NCLS * 4);
    float* g      = (float*)alloc((size_t)NNODE * 512 * 4);

    const int nb = (NNODE + 1023) / 1024;
    const int egrid = (ETOT + 255) / 256;
    const int ngrid = (NNODE + 255) / 256;
    const int wgrid = NNODE / 4;
    const int rtiles = (NNODE + 63) / 64;

    hipMemsetAsync(deg, 0, (size_t)NNODE * 4, stream);
    hipMemsetAsync(fill, 0, (size_t)NNODE * 4, stream);
    k_hist<<<egrid, 256, 0, stream>>>(ei, deg);
    k_scan1<<<nb, 256, 0, stream>>>(deg, rowptr, bsum);
    k_scan2<<<1, 256, 0, stream>>>(bsum, nb);
    k_scan3<<<ngrid, 256, 0, stream>>>(rowptr, bsum);
    k_scatter<<<egrid, 256, 0, stream>>>(ei, rowptr, fill, csr);

    k_gemm<true,  false><<<dim3(rtiles, 1), 256, 0, stream>>>(x, W0, bufA, NNODE, FIN, HID, nullptr);
    k_alpha_hs<<<wgrid, 256, 0, stream>>>(bufA, as0, ad0, asrc, adst);
    k_agg64<<<wgrid, 256, 0, stream>>>(bufA, asrc, adst, rowptr, csr, b0, bufB, 1);

    k_gemm<false, false><<<dim3(rtiles, 1), 256, 0, stream>>>(bufB, W1, bufA, NNODE, HID, HID, nullptr);
    k_alpha_hs<<<wgrid, 256, 0, stream>>>(bufA, as1, ad1, asrc, adst);
    k_agg64<<<wgrid, 256, 0, stream>>>(bufA, asrc, adst, rowptr, csr, b1, bufB, 1);

    k_prep_w2<<<80, 256, 0, stream>>>(W2, as2, ad2, wa, w2r);
    k_alpha2<<<wgrid, 256, 0, stream>>>(bufB, wa, asrc, adst);
    k_agg512<<<wgrid, 256, 0, stream>>>(bufB, asrc, adst, rowptr, csr, g);
    k_gemm<true,  true><<<dim3(rtiles, 1), 256, 0, stream>>>(g, w2r, outp, NNODE, 512, NCLS, b2);
}

// Round 8
// 1090.708 us; speedup vs baseline: 1.1364x; 1.0256x over previous
//
#include <hip/hip_runtime.h>
#include <hip/hip_fp16.h>

// GAT 3-layer forward, MI355X. Round 8:
//  - CSR-by-dst on device; wave-per-node aggregation; scalarized csr; deep
//    ping-pong gather pipeline; no-max softmax; fused bias+log_softmax.
//  - THIS ROUND: fp16 storage for ALL intermediate node features (h0, h0',
//    h1, g), fp32 compute. r7 showed agg512 is byte-volume bound (479MB @
//    2.78 TB/s eff, 53% stall; pipelining saturated). fp16 halves gather rows
//    (256->128B), halves h tables (25.6->12.8MB, better L2 hit), halves g
//    stream (400->200MB round trip) and GEMM A-reads.
//  - Numerics: fp16 err ~5e-4 << 0.0156 absmax floor. Fallback if fail:
//    revert h buffers to f32, keep g fp16.

#define NNODE 100000
#define NEDGE 1600000
#define ETOT  (NNODE + NEDGE)   // 1,700,000 incl self-loops
#define FIN   512
#define HID   64
#define NHEAD 8
#define NCLS  40

typedef float v4f __attribute__((ext_vector_type(4)));

static __device__ __forceinline__ float lrelu(float x) { return x > 0.f ? x : 0.2f * x; }
static __device__ __forceinline__ int rfl(int v) { return __builtin_amdgcn_readfirstlane(v); }

// ---------------- CSR build ----------------
__global__ __launch_bounds__(256) void k_hist(const int* __restrict__ ei, int* __restrict__ deg) {
    int e = blockIdx.x * 256 + threadIdx.x;
    if (e >= ETOT) return;
    int dst = (e < NEDGE) ? ei[NEDGE + e] : (e - NEDGE);
    atomicAdd(&deg[dst], 1);
}

__global__ __launch_bounds__(256) void k_scan1(const int* __restrict__ deg, int* __restrict__ rowptr,
                                               int* __restrict__ bsum) {
    __shared__ int sm[256];
    int b = blockIdx.x, t = threadIdx.x;
    int base = b * 1024 + t * 4;
    int v0=0,v1=0,v2=0,v3=0;
    if (base + 0 < NNODE) v0 = deg[base + 0];
    if (base + 1 < NNODE) v1 = deg[base + 1];
    if (base + 2 < NNODE) v2 = deg[base + 2];
    if (base + 3 < NNODE) v3 = deg[base + 3];
    int tsum = v0 + v1 + v2 + v3;
    sm[t] = tsum;
    __syncthreads();
    int val = tsum;
    for (int off = 1; off < 256; off <<= 1) {
        int y = (t >= off) ? sm[t - off] : 0;
        __syncthreads();
        val += y;
        sm[t] = val;
        __syncthreads();
    }
    int ex = val - tsum;
    if (base + 0 < NNODE) rowptr[base + 0] = ex;
    if (base + 1 < NNODE) rowptr[base + 1] = ex + v0;
    if (base + 2 < NNODE) rowptr[base + 2] = ex + v0 + v1;
    if (base + 3 < NNODE) rowptr[base + 3] = ex + v0 + v1 + v2;
    if (t == 255) bsum[b] = val;
}

__global__ __launch_bounds__(256) void k_scan2(int* __restrict__ bsum, int nb) {
    __shared__ int sm[256];
    int t = threadIdx.x;
    int v = (t < nb) ? bsum[t] : 0;
    sm[t] = v;
    __syncthreads();
    int val = v;
    for (int off = 1; off < 256; off <<= 1) {
        int y = (t >= off) ? sm[t - off] : 0;
        __syncthreads();
        val += y;
        sm[t] = val;
        __syncthreads();
    }
    if (t < nb) bsum[t] = val - v;
}

__global__ __launch_bounds__(256) void k_scan3(int* __restrict__ rowptr, const int* __restrict__ bsum) {
    int i = blockIdx.x * 256 + threadIdx.x;
    if (i < NNODE) rowptr[i] += bsum[i >> 10];
    if (i == 0) rowptr[NNODE] = ETOT;
}

__global__ __launch_bounds__(256) void k_scatter(const int* __restrict__ ei, const int* __restrict__ rowptr,
                                                 int* __restrict__ fill, int* __restrict__ csr) {
    int e = blockIdx.x * 256 + threadIdx.x;
    if (e >= ETOT) return;
    int s, d;
    if (e < NEDGE) { s = ei[e]; d = ei[NEDGE + e]; } else { s = e - NEDGE; d = s; }
    int pos = rowptr[d] + atomicAdd(&fill[d], 1);
    csr[pos] = s;
}

// ---------------- generic fp32-compute GEMM: C = A @ B ----------------
// AH: A operand stored fp16. NTA: non-temporal A loads (streamed once).
// OH: C written fp16. FUSE: bias + log_softmax epilogue (NC==40, f32 out).
template <bool AH, bool NTA, bool OH, bool FUSE>
__global__ __launch_bounds__(256) void k_gemm(const void* __restrict__ Av, const float* __restrict__ B,
                                              void* __restrict__ Cv, int Nrows, int K, int NC,
                                              const float* __restrict__ bias2) {
    __shared__ float As[32][68];
    __shared__ float Bs[32][64];
    int r0 = blockIdx.x * 64;
    int c0 = blockIdx.y * 64;
    int t = threadIdx.x;
    int tx = t & 15, ty = t >> 4;
    float acc[4][4];
    #pragma unroll
    for (int i = 0; i < 4; ++i)
        #pragma unroll
        for (int j = 0; j < 4; ++j) acc[i][j] = 0.f;

    for (int k0 = 0; k0 < K; k0 += 32) {
        if constexpr (AH) {
            // fp16 A stage: thread t loads 8 halves (16B) of row t>>2 at kk=(t&3)*8
            const __half* Ah = (const __half*)Av;
            int row = t >> 2, kk = (t & 3) * 8;
            int gr = r0 + row;
            __half2 hp[4] = {};
            if (gr < Nrows) {
                const v4f* ap = (const v4f*)&Ah[(size_t)gr * K + k0 + kk];
                v4f raw = NTA ? __builtin_nontemporal_load(ap) : *ap;
                *(v4f*)hp = raw;
            }
            #pragma unroll
            for (int i = 0; i < 4; ++i) {
                float2 f = __half22float2(hp[i]);
                As[kk + 2 * i + 0][row] = f.x;
                As[kk + 2 * i + 1][row] = f.y;
            }
        } else {
            const float* Af = (const float*)Av;
            int j = t * 4;
            #pragma unroll
            for (int p = 0; p < 2; ++p) {
                int row = j >> 5, kk = j & 31;
                v4f v = {0.f, 0.f, 0.f, 0.f};
                int gr = r0 + row;
                if (gr < Nrows) {
                    const v4f* ap = (const v4f*)&Af[(size_t)gr * K + k0 + kk];
                    v = NTA ? __builtin_nontemporal_load(ap) : *ap;
                }
                As[kk + 0][row] = v.x; As[kk + 1][row] = v.y;
                As[kk + 2][row] = v.z; As[kk + 3][row] = v.w;
                j += 1024;
            }
        }
        {
            int j = t * 4;
            #pragma unroll
            for (int p = 0; p < 2; ++p) {
                int row = j >> 6, col = j & 63;
                float4 w = make_float4(0.f, 0.f, 0.f, 0.f);
                if (c0 + col < NC) w = *(const float4*)&B[(k0 + row) * NC + c0 + col];
                *(float4*)&Bs[row][col] = w;
                j += 1024;
            }
        }
        __syncthreads();
        #pragma unroll
        for (int kk = 0; kk < 32; ++kk) {
            float4 a = *(const float4*)&As[kk][ty * 4];
            float4 b = *(const float4*)&Bs[kk][tx * 4];
            acc[0][0] = fmaf(a.x, b.x, acc[0][0]); acc[0][1] = fmaf(a.x, b.y, acc[0][1]);
            acc[0][2] = fmaf(a.x, b.z, acc[0][2]); acc[0][3] = fmaf(a.x, b.w, acc[0][3]);
            acc[1][0] = fmaf(a.y, b.x, acc[1][0]); acc[1][1] = fmaf(a.y, b.y, acc[1][1]);
            acc[1][2] = fmaf(a.y, b.z, acc[1][2]); acc[1][3] = fmaf(a.y, b.w, acc[1][3]);
            acc[2][0] = fmaf(a.z, b.x, acc[2][0]); acc[2][1] = fmaf(a.z, b.y, acc[2][1]);
            acc[2][2] = fmaf(a.z, b.z, acc[2][2]); acc[2][3] = fmaf(a.z, b.w, acc[2][3]);
            acc[3][0] = fmaf(a.w, b.x, acc[3][0]); acc[3][1] = fmaf(a.w, b.y, acc[3][1]);
            acc[3][2] = fmaf(a.w, b.z, acc[3][2]); acc[3][3] = fmaf(a.w, b.w, acc[3][3]);
        }
        __syncthreads();
    }

    if constexpr (FUSE) {
        // bias + log_softmax over the 40 cols of each row; f32 output.
        float* C = (float*)Cv;
        __shared__ float smO[64][41];
        __shared__ float smM[64], smL[64];
        #pragma unroll
        for (int i = 0; i < 4; ++i) {
            int rl = ty * 4 + i;
            #pragma unroll
            for (int j = 0; j < 4; ++j) {
                int c = tx * 4 + j;
                if (c < NCLS) smO[rl][c] = acc[i][j] + bias2[c];
            }
        }
        __syncthreads();
        if (t < 64) {
            float mx = -1e30f;
            #pragma unroll 8
            for (int c = 0; c < NCLS; ++c) mx = fmaxf(mx, smO[t][c]);
            float se = 0.f;
            #pragma unroll 8
            for (int c = 0; c < NCLS; ++c) se += __expf(smO[t][c] - mx);
            smM[t] = mx;
            smL[t] = logf(se);
        }
        __syncthreads();
        #pragma unroll
        for (int i = 0; i < 4; ++i) {
            int rl = ty * 4 + i;
            int gr = r0 + rl;
            if (gr < Nrows) {
                float mm = smM[rl], ll = smL[rl];
                #pragma unroll
                for (int j = 0; j < 4; ++j) {
                    int c = tx * 4 + j;
                    if (c < NCLS) C[gr * NCLS + c] = acc[i][j] + bias2[c] - mm - ll;
                }
            }
        }
    } else if constexpr (OH) {
        __half* Ch = (__half*)Cv;
        #pragma unroll
        for (int i = 0; i < 4; ++i) {
            int gr = r0 + ty * 4 + i;
            if (gr < Nrows && (c0 + tx * 4) < NC) {
                __half2 p0 = __floats2half2_rn(acc[i][0], acc[i][1]);
                __half2 p1 = __floats2half2_rn(acc[i][2], acc[i][3]);
                uint2 u;
                u.x = *(unsigned int*)&p0;
                u.y = *(unsigned int*)&p1;
                *(uint2*)&Ch[(size_t)gr * NC + c0 + tx * 4] = u;
            }
        }
    } else {
        float* C = (float*)Cv;
        #pragma unroll
        for (int i = 0; i < 4; ++i) {
            int gr = r0 + ty * 4 + i;
            if (gr < Nrows && (c0 + tx * 4) < NC) {
                float4 o = make_float4(acc[i][0], acc[i][1], acc[i][2], acc[i][3]);
                *(float4*)&C[gr * NC + c0 + tx * 4] = o;
            }
        }
    }
}

// ---------------- alpha for head-sliced features (layers 0/1), fp16 h ----------------
__global__ __launch_bounds__(256) void k_alpha_hs(const __half* __restrict__ hp, const float* __restrict__ a_s,
                                                  const float* __restrict__ a_d,
                                                  float* __restrict__ asrc, float* __restrict__ adst) {
    int t = threadIdx.x;
    int lane = t & 63;
    int n = (blockIdx.x * 256 + t) >> 6;
    if (n >= NNODE) return;
    float v = __half2float(hp[n * 64 + lane]);
    float s = v * a_s[lane];
    float d = v * a_d[lane];
    s += __shfl_xor(s, 1); s += __shfl_xor(s, 2); s += __shfl_xor(s, 4);
    d += __shfl_xor(d, 1); d += __shfl_xor(d, 2); d += __shfl_xor(d, 4);
    if ((lane & 7) == 0) {
        asrc[n * 8 + (lane >> 3)] = s;
        adst[n * 8 + (lane >> 3)] = d;
    }
}

// ---- pipelined index/value window helpers (fp16 h gather) ----
#define LD_IDX(S0,S1,S2,S3,BASE)                         \
    S0 = rfl(csr[min((BASE) + 0, e1)]);                  \
    S1 = rfl(csr[min((BASE) + 1, e1)]);                  \
    S2 = rfl(csr[min((BASE) + 2, e1)]);                  \
    S3 = rfl(csr[min((BASE) + 3, e1)]);

#define LD_VAL(S0,S1,S2,S3,V0,V1,V2,V3,A0,A1,A2,A3)                      \
    V0 = __half2float(hp[S0 * 64 + lane]);  A0 = asrc[S0 * 8 + hh];     \
    V1 = __half2float(hp[S1 * 64 + lane]);  A1 = asrc[S1 * 8 + hh];     \
    V2 = __half2float(hp[S2 * 64 + lane]);  A2 = asrc[S2 * 8 + hh];     \
    V3 = __half2float(hp[S3 * 64 + lane]);  A3 = asrc[S3 * 8 + hh];

// ---------------- aggregation layers 0/1 (64 feats): fp16 h in/out ----------------
__global__ __launch_bounds__(256) void k_agg64(const __half* __restrict__ hp, const float* __restrict__ asrc,
                                               const float* __restrict__ adst, const int* __restrict__ rowptr,
                                               const int* __restrict__ csr, const float* __restrict__ bias,
                                               __half* __restrict__ out, int doElu) {
    int t = threadIdx.x;
    int lane = t & 63;
    int n = (blockIdx.x * 256 + t) >> 6;
    if (n >= NNODE) return;
    int start = rfl(rowptr[n]);
    int end   = rfl(rowptr[n + 1]);
    int e1 = end - 1;
    int hh = lane >> 3;                 // head in feature layout (lane = h*8+c)
    float ad = adst[n * 8 + hh];

    int   sA0,sA1,sA2,sA3, sB0,sB1,sB2,sB3;
    float vA0,vA1,vA2,vA3, aA0,aA1,aA2,aA3;
    float vB0,vB1,vB2,vB3, aB0,aB1,aB2,aB3;
    LD_IDX(sA0,sA1,sA2,sA3, start)
    LD_VAL(sA0,sA1,sA2,sA3, vA0,vA1,vA2,vA3, aA0,aA1,aA2,aA3)
    LD_IDX(sB0,sB1,sB2,sB3, start + 4)
    LD_VAL(sB0,sB1,sB2,sB3, vB0,vB1,vB2,vB3, aB0,aB1,aB2,aB3)

    float acc = 0.f, ssum = 0.f;
    #define EDGE64(AV,AA,COND)                                        \
        if (COND) {                                                   \
            float x_ = __expf(fminf(lrelu((AA) + ad), 80.f));         \
            ssum += x_;                                               \
            acc = fmaf(x_, (AV), acc);                                \
        }
    for (int base = start; base < end; base += 8) {
        EDGE64(vA0, aA0, true)
        EDGE64(vA1, aA1, base + 1 < end)
        EDGE64(vA2, aA2, base + 2 < end)
        EDGE64(vA3, aA3, base + 3 < end)
        if (base + 8 < end) {
            LD_IDX(sA0,sA1,sA2,sA3, base + 8)
            LD_VAL(sA0,sA1,sA2,sA3, vA0,vA1,vA2,vA3, aA0,aA1,aA2,aA3)
        }
        EDGE64(vB0, aB0, base + 4 < end)
        EDGE64(vB1, aB1, base + 5 < end)
        EDGE64(vB2, aB2, base + 6 < end)
        EDGE64(vB3, aB3, base + 7 < end)
        if (base + 12 < end) {
            LD_IDX(sB0,sB1,sB2,sB3, base + 12)
            LD_VAL(sB0,sB1,sB2,sB3, vB0,vB1,vB2,vB3, aB0,aB1,aB2,aB3)
        }
    }
    #undef EDGE64
    float o = acc / (ssum + 1e-16f) + bias[lane];
    if (doElu) o = (o > 0.f) ? o : expm1f(o);
    out[n * 64 + lane] = __float2half(o);
}

// ---------------- layer-2 weight precompute ----------------
__global__ __launch_bounds__(256) void k_prep_w2(const float* __restrict__ W2, const float* __restrict__ as2,
                                                 const float* __restrict__ ad2,
                                                 float* __restrict__ wa, float* __restrict__ w2r) {
    int idx = blockIdx.x * 256 + threadIdx.x;
    if (idx < 1024) {
        int which = idx >> 9;
        int hh = (idx >> 6) & 7, k = idx & 63;
        const float* a = which ? ad2 : as2;
        float s = 0.f;
        #pragma unroll 8
        for (int c = 0; c < NCLS; ++c) s += W2[k * 320 + hh * 40 + c] * a[hh * 40 + c];
        wa[idx] = s;
    }
    for (int j2 = idx; j2 < 512 * NCLS; j2 += gridDim.x * 256) {
        int rc = j2 / NCLS, c = j2 - rc * NCLS;
        int hh = rc >> 6, k = rc & 63;
        w2r[j2] = W2[k * 320 + hh * 40 + c] * 0.125f;
    }
}

// ---------------- alpha for layer 2 (fp16 h1) ----------------
__global__ __launch_bounds__(256) void k_alpha2(const __half* __restrict__ hp, const float* __restrict__ wa,
                                                float* __restrict__ asrc, float* __restrict__ adst) {
    __shared__ float ws[1024];
    int t = threadIdx.x;
    for (int j = t; j < 1024; j += 256) ws[j] = wa[j];
    __syncthreads();
    int lane = t & 63;
    int n = (blockIdx.x * 256 + t) >> 6;
    if (n >= NNODE) return;
    float v = __half2float(hp[n * 64 + lane]);
    #pragma unroll
    for (int hh = 0; hh < 8; ++hh) {
        float s = v * ws[hh * 64 + lane];
        float d = v * ws[512 + hh * 64 + lane];
        #pragma unroll
        for (int mk = 32; mk; mk >>= 1) { s += __shfl_xor(s, mk); d += __shfl_xor(d, mk); }
        if (lane == 0) { asrc[n * 8 + hh] = s; adst[n * 8 + hh] = d; }
    }
}

// ---------------- layer-2 aggregation: fp16 h1 in, fp16 g out (nt) ----------------
__global__ __launch_bounds__(256) void k_agg512(const __half* __restrict__ hp, const float* __restrict__ asrc,
                                                const float* __restrict__ adst, const int* __restrict__ rowptr,
                                                const int* __restrict__ csr, __half* __restrict__ g) {
    int t = threadIdx.x;
    int lane = t & 63;
    int n = (blockIdx.x * 256 + t) >> 6;
    if (n >= NNODE) return;
    int start = rfl(rowptr[n]);
    int end   = rfl(rowptr[n + 1]);
    int e1 = end - 1;
    int hh = lane & 7;                  // head owned by this lane for alpha
    float ad = adst[n * 8 + hh];

    int   sA0,sA1,sA2,sA3, sB0,sB1,sB2,sB3;
    float vA0,vA1,vA2,vA3, aA0,aA1,aA2,aA3;
    float vB0,vB1,vB2,vB3, aB0,aB1,aB2,aB3;
    LD_IDX(sA0,sA1,sA2,sA3, start)
    LD_VAL(sA0,sA1,sA2,sA3, vA0,vA1,vA2,vA3, aA0,aA1,aA2,aA3)
    LD_IDX(sB0,sB1,sB2,sB3, start + 4)
    LD_VAL(sB0,sB1,sB2,sB3, vB0,vB1,vB2,vB3, aB0,aB1,aB2,aB3)

    float acc[8];
    #pragma unroll
    for (int k = 0; k < 8; ++k) acc[k] = 0.f;
    float ssum = 0.f;

    #define EDGE512(AV,AA,COND)                                       \
        if (COND) {                                                   \
            float x_ = __expf(fminf(lrelu((AA) + ad), 80.f));         \
            ssum += x_;                                               \
            float x0_ = __shfl(x_, 0); acc[0] = fmaf(x0_, (AV), acc[0]); \
            float x1_ = __shfl(x_, 1); acc[1] = fmaf(x1_, (AV), acc[1]); \
            float x2_ = __shfl(x_, 2); acc[2] = fmaf(x2_, (AV), acc[2]); \
            float x3_ = __shfl(x_, 3); acc[3] = fmaf(x3_, (AV), acc[3]); \
            float x4_ = __shfl(x_, 4); acc[4] = fmaf(x4_, (AV), acc[4]); \
            float x5_ = __shfl(x_, 5); acc[5] = fmaf(x5_, (AV), acc[5]); \
            float x6_ = __shfl(x_, 6); acc[6] = fmaf(x6_, (AV), acc[6]); \
            float x7_ = __shfl(x_, 7); acc[7] = fmaf(x7_, (AV), acc[7]); \
        }
    for (int base = start; base < end; base += 8) {
        EDGE512(vA0, aA0, true)
        EDGE512(vA1, aA1, base + 1 < end)
        EDGE512(vA2, aA2, base + 2 < end)
        EDGE512(vA3, aA3, base + 3 < end)
        if (base + 8 < end) {
            LD_IDX(sA0,sA1,sA2,sA3, base + 8)
            LD_VAL(sA0,sA1,sA2,sA3, vA0,vA1,vA2,vA3, aA0,aA1,aA2,aA3)
        }
        EDGE512(vB0, aB0, base + 4 < end)
        EDGE512(vB1, aB1, base + 5 < end)
        EDGE512(vB2, aB2, base + 6 < end)
        EDGE512(vB3, aB3, base + 7 < end)
        if (base + 12 < end) {
            LD_IDX(sB0,sB1,sB2,sB3, base + 12)
            LD_VAL(sB0,sB1,sB2,sB3, vB0,vB1,vB2,vB3, aB0,aB1,aB2,aB3)
        }
    }
    #undef EDGE512

    #pragma unroll
    for (int k = 0; k < 8; ++k) {
        float sh = __shfl(ssum, k);
        __half hv = __float2half(acc[k] / (sh + 1e-16f));
        unsigned short us = *(unsigned short*)&hv;
        __builtin_nontemporal_store(us, (unsigned short*)&g[n * 512 + k * 64 + lane]);
    }
}

// ---------------- launch ----------------
extern "C" void kernel_launch(void* const* d_in, const int* in_sizes, int n_in,
                              void* d_out, int out_size, void* d_ws, size_t ws_size,
                              hipStream_t stream) {
    (void)in_sizes; (void)n_in; (void)out_size; (void)ws_size;
    const float* x   = (const float*)d_in[0];
    const int*   ei  = (const int*)d_in[1];
    const float* W0  = (const float*)d_in[2];
    const float* as0 = (const float*)d_in[3];
    const float* ad0 = (const float*)d_in[4];
    const float* b0  = (const float*)d_in[5];
    const float* W1  = (const float*)d_in[6];
    const float* as1 = (const float*)d_in[7];
    const float* ad1 = (const float*)d_in[8];
    const float* b1  = (const float*)d_in[9];
    const float* W2  = (const float*)d_in[10];
    const float* as2 = (const float*)d_in[11];
    const float* ad2 = (const float*)d_in[12];
    const float* b2  = (const float*)d_in[13];
    float* outp = (float*)d_out;

    size_t off = 0;
    auto alloc = [&](size_t bytes) -> void* {
        void* p = (char*)d_ws + off;
        off += (bytes + 255) & ~(size_t)255;
        return p;
    };
    int*    deg    = (int*)alloc((size_t)NNODE * 4);
    int*    fill   = (int*)alloc((size_t)NNODE * 4);
    int*    rowptr = (int*)alloc((size_t)(NNODE + 1) * 4);
    int*    bsum   = (int*)alloc(256 * 4);
    int*    csr    = (int*)alloc((size_t)ETOT * 4);
    float*  asrc   = (float*)alloc((size_t)NNODE * 8 * 4);
    float*  adst   = (float*)alloc((size_t)NNODE * 8 * 4);
    __half* bufA   = (__half*)alloc((size_t)NNODE * 64 * 2);   // h0 / h1 (fp16)
    __half* bufB   = (__half*)alloc((size_t)NNODE * 64 * 2);   // h0' (fp16)
    float*  wa     = (float*)alloc(1024 * 4);
    float*  w2r    = (float*)alloc((size_t)512 * NCLS * 4);
    __half* g      = (__half*)alloc((size_t)NNODE * 512 * 2);  // fp16 g

    const int nb = (NNODE + 1023) / 1024;
    const int egrid = (ETOT + 255) / 256;
    const int ngrid = (NNODE + 255) / 256;
    const int wgrid = NNODE / 4;
    const int rtiles = (NNODE + 63) / 64;

    hipMemsetAsync(deg, 0, (size_t)NNODE * 4, stream);
    hipMemsetAsync(fill, 0, (size_t)NNODE * 4, stream);
    k_hist<<<egrid, 256, 0, stream>>>(ei, deg);
    k_scan1<<<nb, 256, 0, stream>>>(deg, rowptr, bsum);
    k_scan2<<<1, 256, 0, stream>>>(bsum, nb);
    k_scan3<<<ngrid, 256, 0, stream>>>(rowptr, bsum);
    k_scatter<<<egrid, 256, 0, stream>>>(ei, rowptr, fill, csr);

    // layer 0: x(f32) @ W0 -> h0 fp16
    k_gemm<false, true, true, false><<<dim3(rtiles, 1), 256, 0, stream>>>(x, W0, bufA, NNODE, FIN, HID, nullptr);
    k_alpha_hs<<<wgrid, 256, 0, stream>>>(bufA, as0, ad0, asrc, adst);
    k_agg64<<<wgrid, 256, 0, stream>>>(bufA, asrc, adst, rowptr, csr, b0, bufB, 1);

    // layer 1: h0'(fp16) @ W1 -> h1 fp16
    k_gemm<true, false, true, false><<<dim3(rtiles, 1), 256, 0, stream>>>(bufB, W1, bufA, NNODE, HID, HID, nullptr);
    k_alpha_hs<<<wgrid, 256, 0, stream>>>(bufA, as1, ad1, asrc, adst);
    k_agg64<<<wgrid, 256, 0, stream>>>(bufA, asrc, adst, rowptr, csr, b1, bufB, 1);

    // layer 2: aggregate h1 per head -> g fp16; g @ w2r + bias + log_softmax -> out f32
    k_prep_w2<<<80, 256, 0, stream>>>(W2, as2, ad2, wa, w2r);
    k_alpha2<<<wgrid, 256, 0, stream>>>(bufB, wa, asrc, adst);
    k_agg512<<<wgrid, 256, 0, stream>>>(bufB, asrc, adst, rowptr, csr, g);
    k_gemm<true, true, false, true><<<dim3(rtiles, 1), 256, 0, stream>>>(g, w2r, outp, NNODE, 512, NCLS, b2);
}